// Round 6
// baseline (475.747 us; speedup 1.0000x reference)
//
#include <hip/hip_runtime.h>
#include <hip/hip_bf16.h>

#define BB 512
#define TT 256

typedef __attribute__((ext_vector_type(8))) short bf16x8;
typedef __attribute__((ext_vector_type(4))) float f32x4;

__device__ __forceinline__ unsigned short f2b(float f) {
    union { float f; unsigned u; } v; v.f = f;
    unsigned r = v.u + 0x7FFFu + ((v.u >> 16) & 1u);
    return (unsigned short)(r >> 16);
}
__device__ __forceinline__ float b2f(unsigned short h) {
    union { unsigned u; float f; } v; v.u = ((unsigned)h) << 16;
    return v.f;
}
__device__ __forceinline__ ushort2 pk2(float a, float b) {
    __hip_bfloat162 h = __float22bfloat162_rn(float2{a, b});
    union { __hip_bfloat162 h; ushort2 u; } v; v.h = h; return v.u;
}

// B-layout per (s,t): 16-batch x K shorts, addr(b,k) = (k>>3)*128 + b*8 + (k&7).
// B-frag kc = one b128 at kc*512 + rdo (rdo = quad*128 + l15*8);
// D-tile mt write = ushort4 at wro + mt*256.

// ---------------- fp32 x -> bf16 B-layout tiles (r5: LDS transpose) ---------
__global__ __launch_bounds__(256) void cvt_tile4(const float* __restrict__ x,
                                                 unsigned short* __restrict__ xb) {
    __shared__ float xs[16][260];
    const int s = blockIdx.x >> 6;          // 0..31
    const int tg = blockIdx.x & 63;         // 0..63, 4 t's per block
    const int tid = threadIdx.x;
    const float* xbase = x + ((size_t)(s * 16) * TT + tg * 4) * 64;
#pragma unroll
    for (int it = 0; it < 4; ++it) {
        const int b = it * 4 + (tid >> 6);
        const int r = tid & 63;
        float4 v = *reinterpret_cast<const float4*>(xbase + (size_t)b * (TT * 64) + r * 4);
        *reinterpret_cast<float4*>(&xs[b][r * 4]) = v;
    }
    __syncthreads();
#pragma unroll
    for (int it = 0; it < 2; ++it) {
        const int t = it * 2 + (tid >> 7);
        const int oct = (tid >> 4) & 7;
        const int b = tid & 15;
        const float* src = &xs[b][t * 64 + oct * 8];
        float4 va = *reinterpret_cast<const float4*>(src);
        float4 vb = *reinterpret_cast<const float4*>(src + 4);
        ushort2 p0 = pk2(va.x, va.y), p1 = pk2(va.z, va.w);
        ushort2 p2 = pk2(vb.x, vb.y), p3 = pk2(vb.z, vb.w);
        ushort4 lo; lo.x = p0.x; lo.y = p0.y; lo.z = p1.x; lo.w = p1.y;
        ushort4 hi; hi.x = p2.x; hi.y = p2.y; hi.z = p3.x; hi.w = p3.y;
        unsigned short* ob = xb + ((size_t)(s * TT) + tg * 4 + t) * 1024 + oct * 128 + b * 8;
        *reinterpret_cast<ushort4*>(ob) = lo;
        *reinterpret_cast<ushort4*>(ob + 4) = hi;
    }
}

// ---------------- 4-layer skewed fused RNN, flag-pipelined ------------------
// Round-6: SAME wave roles / schedule / guards / numerics as the 325µs
// winner, but the per-step all-wave barrier is replaced by per-wave progress
// flags + LDS TRIPLE buffering. With double-buffer, write-hazards make every
// wave depend on all 8 (flags would re-implement the barrier); with lag-2
// hazards (triple buffer) the graph is a DAG:
//   read deps @ i-1:  w0/w1:{0,1,6,7}=0xC3  L2:{0..5}=0x3F  L3:{2..7}=0xFC
//   write haz @ i-2:  w0/w1:{0..5}=0x3F     L2:{2..7}=0xFC  L3:{0,1,6,7}=0xC3
// Steady state then collapses toward the per-SIMD MFMA-pipe floor (~1862cyc
// vs 2991 measured with barrier). Publish = lgkmcnt(0) -> flag; consume =
// volatile spin + s_sleep(1); asm memory clobbers pin compile-time order.
// Deadlock-free: every wave publishes every step unconditionally, thresholds
// only reference i-1/i-2, counters monotonic (no ABA).
__global__ __launch_bounds__(512) __attribute__((amdgpu_waves_per_eu(2, 2))) void rnn4(
    const unsigned short* __restrict__ Xb,
    const float* __restrict__ Wx1, const float* __restrict__ Wh1, const float* __restrict__ b1,
    const float* __restrict__ Wx2, const float* __restrict__ Wh2, const float* __restrict__ b2,
    const float* __restrict__ Wx3, const float* __restrict__ Wh3, const float* __restrict__ b3,
    const float* __restrict__ Wx4, const float* __restrict__ Wh4, const float* __restrict__ b4,
    unsigned short* __restrict__ H4,
    const float* __restrict__ Wd, const float* __restrict__ bd,
    float* __restrict__ out) {
    const int tid = threadIdx.x;
    const int s = blockIdx.x;
    const int w = tid >> 6;
    const int lane = tid & 63;
    const int l15 = lane & 15;
    const int quad = lane >> 4;
    const int rdo = quad * 128 + l15 * 8;

    // Per buffer: h1[0,2048) h2[2048,6144) h3[6144,8192) h4[8192,9216). x3.
    __shared__ __align__(16) unsigned short hall[3][9216];
    __shared__ int prog[8];

    bf16x8 wreg[48];
    f32x4 bvv[6];

#define LOADW(BASE, WP, H_, CB, KC_, MT_)                                          \
    _Pragma("unroll")                                                              \
    for (int mt = 0; mt < MT_; ++mt) {                                             \
        int m = (CB) + mt * 16 + l15;                                              \
        _Pragma("unroll")                                                          \
        for (int kc = 0; kc < KC_; ++kc)                                           \
            _Pragma("unroll")                                                      \
            for (int j = 0; j < 8; ++j)                                            \
                wreg[(BASE) + kc * MT_ + mt][j] =                                  \
                    (short)f2b(WP[(kc * 32 + quad * 8 + j) * H_ + m]);             \
    }
#define LOADBF(OFF, BP, CB, MT_)                                                   \
    _Pragma("unroll")                                                              \
    for (int mt = 0; mt < MT_; ++mt) {                                             \
        float4 t4v = *reinterpret_cast<const float4*>((BP) + (CB) + mt * 16 + quad * 4); \
        bvv[(OFF) + mt][0] = t4v.x; bvv[(OFF) + mt][1] = t4v.y;                    \
        bvv[(OFF) + mt][2] = t4v.z; bvv[(OFF) + mt][3] = t4v.w;                    \
    }

    if (w < 2) {
        LOADW(0,  Wh1, 128, w * 64, 4, 4)
        LOADW(16, Wx1, 128, w * 64, 2, 4)
        LOADW(24, Wh4, 64,  w * 32, 2, 2)
        LOADW(28, Wx4, 64,  w * 32, 4, 2)
        LOADBF(0, b1, w * 64, 4)
        LOADBF(4, b4, w * 32, 2)
    } else if (w < 6) {
        __builtin_amdgcn_s_setprio(1);
        LOADW(0,  Wh2, 256, (w - 2) * 64, 8, 4)
        LOADW(32, Wx2, 256, (w - 2) * 64, 4, 4)
        LOADBF(0, b2, (w - 2) * 64, 4)
    } else {
        LOADW(0,  Wh3, 128, (w - 6) * 64, 4, 4)
        LOADW(16, Wx3, 128, (w - 6) * 64, 8, 4)
        LOADBF(0, b3, (w - 6) * 64, 4)
    }
#undef LOADW
#undef LOADBF

    for (int i = tid; i < 3 * 9216; i += 512) (&hall[0][0])[i] = 0;
    if (tid < 8) prog[tid] = -1;

    const unsigned short* Xs = Xb + (size_t)s * TT * 1024;
    unsigned short* H4s = H4 + (size_t)s * TT * 1024;

    // x parity prefetch into wreg[36..39]: [36,37] even t, [38,39] odd t
    if (w < 2) {
#pragma unroll
        for (int kx = 0; kx < 2; ++kx) {
            wreg[36 + kx] = *reinterpret_cast<const bf16x8*>(&Xs[kx * 512 + rdo]);
            wreg[38 + kx] = *reinterpret_cast<const bf16x8*>(&Xs[1024 + kx * 512 + rdo]);
        }
    }
    __syncthreads();

    const unsigned short* xp0 = Xs + 2 * 1024 + rdo;   // even prefetch target
    const unsigned short* xp1 = Xs + 3 * 1024 + rdo;   // odd

    const int wro1 = (w * 8 + (quad >> 1)) * 128 + l15 * 8 + (quad & 1) * 4;
    const int wro4 = 8192 + (w * 4 + (quad >> 1)) * 128 + l15 * 8 + (quad & 1) * 4;
    const int wro2 = 2048 + ((w - 2) * 8 + (quad >> 1)) * 128 + l15 * 8 + (quad & 1) * 4;
    const int wro3 = 6144 + ((w - 6) * 8 + (quad >> 1)) * 128 + l15 * 8 + (quad & 1) * 4;

    // L4 direct global store: even-macro stores odd t4; odd-macro stores even.
    unsigned short* op_e = H4s + 1024 + (wro4 - 8192);  // first even-macro t4 = 1
    unsigned short* op_o = H4s + (wro4 - 8192);         // first odd-macro  t4 = 0

#define PACKMK(ACC_MT)                                                             \
    ushort2 lo = pk2(fmaxf((ACC_MT)[0], 0.f), fmaxf((ACC_MT)[1], 0.f));            \
    ushort2 hi = pk2(fmaxf((ACC_MT)[2], 0.f), fmaxf((ACC_MT)[3], 0.f));            \
    ushort4 o; o.x = lo.x; o.y = lo.y; o.z = hi.x; o.w = hi.y;

// Wait until prog[l] >= i-1 for l in M1_, >= i-2 for l in M2_.
#define POLL(I_, M1_, M2_)                                                         \
    {                                                                              \
        int thr_;                                                                  \
        if (lane < 8)                                                              \
            thr_ = (((M1_) >> lane) & 1) ? (I_) - 1                                \
                 : ((((M2_) >> lane) & 1) ? (I_) - 2 : (int)0x80000000);           \
        else                                                                       \
            thr_ = (int)0x80000000;                                                \
        while (true) {                                                             \
            int v_ = *(volatile int*)&prog[lane & 7];                              \
            if (__all(v_ >= thr_)) break;                                          \
            __builtin_amdgcn_s_sleep(1);                                           \
        }                                                                          \
        asm volatile("" ::: "memory");                                             \
    }

#define PUBLISH(I_)                                                                \
    asm volatile("" ::: "memory");                                                 \
    __builtin_amdgcn_s_waitcnt(0xC07F);                                            \
    asm volatile("" ::: "memory");                                                 \
    if (lane == 0) *(volatile int*)&prog[w] = (I_);                                \
    asm volatile("" ::: "memory");

#define STEP(TAU_, RBP_, WBP_, XAB, XPP, OPP)                                      \
    {                                                                              \
        const int tau_ = (TAU_);                                                   \
        const unsigned short* RB = (RBP_);                                         \
        unsigned short* WB = (WBP_);                                               \
        if (w < 2) {                                                               \
            POLL(tau_, 0xC3, 0x3F)                                                 \
            if ((unsigned)tau_ < TT) { /* L1 */                                    \
                f32x4 acc[4];                                                      \
                _Pragma("unroll")                                                  \
                for (int mt = 0; mt < 4; ++mt)                                     \
                    acc[mt] = __builtin_amdgcn_mfma_f32_16x16x32_bf16(             \
                        wreg[16 + mt], wreg[(XAB) + 0], bvv[mt], 0, 0, 0);         \
                _Pragma("unroll")                                                  \
                for (int mt = 0; mt < 4; ++mt)                                     \
                    acc[mt] = __builtin_amdgcn_mfma_f32_16x16x32_bf16(             \
                        wreg[20 + mt], wreg[(XAB) + 1], acc[mt], 0, 0, 0);         \
                if (tau_ + 2 < TT) {                                               \
                    wreg[(XAB) + 0] = *reinterpret_cast<const bf16x8*>(XPP);       \
                    wreg[(XAB) + 1] = *reinterpret_cast<const bf16x8*>(XPP + 512); \
                    XPP += 2048;                                                   \
                }                                                                  \
                _Pragma("unroll")                                                  \
                for (int kc = 0; kc < 4; ++kc) {                                   \
                    bf16x8 af = *reinterpret_cast<const bf16x8*>(&RB[rdo + kc * 512]); \
                    _Pragma("unroll")                                              \
                    for (int mt = 0; mt < 4; ++mt)                                 \
                        acc[mt] = __builtin_amdgcn_mfma_f32_16x16x32_bf16(         \
                            wreg[kc * 4 + mt], af, acc[mt], 0, 0, 0);              \
                }                                                                  \
                _Pragma("unroll")                                                  \
                for (int mt = 0; mt < 4; ++mt) {                                   \
                    PACKMK(acc[mt])                                                \
                    *reinterpret_cast<ushort4*>(&WB[wro1 + mt * 256]) = o;         \
                }                                                                  \
            }                                                                      \
            if ((unsigned)(tau_ - 3) < TT) { /* L4 */                              \
                f32x4 acc[2];                                                      \
                {                                                                  \
                    bf16x8 af0 = *reinterpret_cast<const bf16x8*>(&RB[6144 + rdo]); \
                    _Pragma("unroll")                                              \
                    for (int mt = 0; mt < 2; ++mt)                                 \
                        acc[mt] = __builtin_amdgcn_mfma_f32_16x16x32_bf16(         \
                            wreg[28 + mt], af0, bvv[4 + mt], 0, 0, 0);             \
                }                                                                  \
                _Pragma("unroll")                                                  \
                for (int kx = 1; kx < 4; ++kx) {                                   \
                    bf16x8 af = *reinterpret_cast<const bf16x8*>(&RB[6144 + rdo + kx * 512]); \
                    _Pragma("unroll")                                              \
                    for (int mt = 0; mt < 2; ++mt)                                 \
                        acc[mt] = __builtin_amdgcn_mfma_f32_16x16x32_bf16(         \
                            wreg[28 + kx * 2 + mt], af, acc[mt], 0, 0, 0);         \
                }                                                                  \
                _Pragma("unroll")                                                  \
                for (int kc = 0; kc < 2; ++kc) {                                   \
                    bf16x8 af = *reinterpret_cast<const bf16x8*>(&RB[8192 + rdo + kc * 512]); \
                    _Pragma("unroll")                                              \
                    for (int mt = 0; mt < 2; ++mt)                                 \
                        acc[mt] = __builtin_amdgcn_mfma_f32_16x16x32_bf16(         \
                            wreg[24 + kc * 2 + mt], af, acc[mt], 0, 0, 0);         \
                }                                                                  \
                _Pragma("unroll")                                                  \
                for (int mt = 0; mt < 2; ++mt) {                                   \
                    PACKMK(acc[mt])                                                \
                    *reinterpret_cast<ushort4*>(&WB[wro4 + mt * 256]) = o;         \
                    *reinterpret_cast<ushort4*>(OPP + mt * 256) = o;               \
                }                                                                  \
                OPP += 2048;                                                       \
            }                                                                      \
        } else if (w < 6) {                                                        \
            POLL(tau_, 0x3F, 0xFC)                                                 \
            if ((unsigned)(tau_ - 1) < TT) { /* L2 */                              \
                f32x4 acc[4];                                                      \
                {                                                                  \
                    bf16x8 af0 = *reinterpret_cast<const bf16x8*>(&RB[rdo]);       \
                    _Pragma("unroll")                                              \
                    for (int mt = 0; mt < 4; ++mt)                                 \
                        acc[mt] = __builtin_amdgcn_mfma_f32_16x16x32_bf16(         \
                            wreg[32 + mt], af0, bvv[mt], 0, 0, 0);                 \
                }                                                                  \
                _Pragma("unroll")                                                  \
                for (int kx = 1; kx < 4; ++kx) {                                   \
                    bf16x8 af = *reinterpret_cast<const bf16x8*>(&RB[rdo + kx * 512]); \
                    _Pragma("unroll")                                              \
                    for (int mt = 0; mt < 4; ++mt)                                 \
                        acc[mt] = __builtin_amdgcn_mfma_f32_16x16x32_bf16(         \
                            wreg[32 + kx * 4 + mt], af, acc[mt], 0, 0, 0);         \
                }                                                                  \
                _Pragma("unroll")                                                  \
                for (int kc = 0; kc < 8; ++kc) {                                   \
                    bf16x8 af = *reinterpret_cast<const bf16x8*>(&RB[2048 + rdo + kc * 512]); \
                    _Pragma("unroll")                                              \
                    for (int mt = 0; mt < 4; ++mt)                                 \
                        acc[mt] = __builtin_amdgcn_mfma_f32_16x16x32_bf16(         \
                            wreg[kc * 4 + mt], af, acc[mt], 0, 0, 0);              \
                }                                                                  \
                _Pragma("unroll")                                                  \
                for (int mt = 0; mt < 4; ++mt) {                                   \
                    PACKMK(acc[mt])                                                \
                    *reinterpret_cast<ushort4*>(&WB[wro2 + mt * 256]) = o;         \
                }                                                                  \
            }                                                                      \
        } else {                                                                   \
            POLL(tau_, 0xFC, 0xC3)                                                 \
            if ((unsigned)(tau_ - 2) < TT) { /* L3 */                              \
                f32x4 acc[4];                                                      \
                {                                                                  \
                    bf16x8 af0 = *reinterpret_cast<const bf16x8*>(&RB[2048 + rdo]); \
                    _Pragma("unroll")                                              \
                    for (int mt = 0; mt < 4; ++mt)                                 \
                        acc[mt] = __builtin_amdgcn_mfma_f32_16x16x32_bf16(         \
                            wreg[16 + mt], af0, bvv[mt], 0, 0, 0);                 \
                }                                                                  \
                _Pragma("unroll")                                                  \
                for (int kx = 1; kx < 8; ++kx) {                                   \
                    bf16x8 af = *reinterpret_cast<const bf16x8*>(&RB[2048 + rdo + kx * 512]); \
                    _Pragma("unroll")                                              \
                    for (int mt = 0; mt < 4; ++mt)                                 \
                        acc[mt] = __builtin_amdgcn_mfma_f32_16x16x32_bf16(         \
                            wreg[16 + kx * 4 + mt], af, acc[mt], 0, 0, 0);         \
                }                                                                  \
                _Pragma("unroll")                                                  \
                for (int kc = 0; kc < 4; ++kc) {                                   \
                    bf16x8 af = *reinterpret_cast<const bf16x8*>(&RB[6144 + rdo + kc * 512]); \
                    _Pragma("unroll")                                              \
                    for (int mt = 0; mt < 4; ++mt)                                 \
                        acc[mt] = __builtin_amdgcn_mfma_f32_16x16x32_bf16(         \
                            wreg[kc * 4 + mt], af, acc[mt], 0, 0, 0);              \
                }                                                                  \
                _Pragma("unroll")                                                  \
                for (int mt = 0; mt < 4; ++mt) {                                   \
                    PACKMK(acc[mt])                                                \
                    *reinterpret_cast<ushort4*>(&WB[wro3 + mt * 256]) = o;         \
                }                                                                  \
            }                                                                      \
        }                                                                          \
        PUBLISH(tau_)                                                              \
    }

    // Rotating triple-buffer pointers: step i reads buf[(i-1)%3], writes
    // buf[i%3]. Step 0 reads the zeroed hall[2] ("step -1").
    unsigned short* bprv = &hall[2][0];
    unsigned short* bcur = &hall[0][0];
    unsigned short* bnxt = &hall[1][0];

#pragma unroll 1
    for (int tau = 0; tau < TT + 3; tau += 2) {
        STEP(tau, bprv, bcur, 36, xp0, op_e)
        { unsigned short* t_ = bprv; bprv = bcur; bcur = bnxt; bnxt = t_; }
        STEP(tau + 1, bprv, bcur, 38, xp1, op_o)
        { unsigned short* t_ = bprv; bprv = bcur; bcur = bnxt; bnxt = t_; }
    }
#undef STEP
#undef POLL
#undef PUBLISH
#undef PACKMK

    // ---- fused dense epilogue (post-loop, transient regs only) -------------
    // out[s*16+b] = bd + sum_t h4[b,t,:].Wd[t*64:]. Block-local H4 readback
    // (L2-hot). w0/w1 drain their L4 stores; barrier makes them visible.
    __builtin_amdgcn_s_waitcnt(0x0F70);   // vmcnt(0)
    __syncthreads();
    {
        float dacc = 0.f;
        const unsigned short* gb = H4s + quad * 128 + l15 * 8;
        const float* wb = Wd + quad * 8;
#pragma unroll 4
        for (int ti = 0; ti < 32; ++ti) {
            const int t = w + ti * 8;
            bf16x8 h0 = *reinterpret_cast<const bf16x8*>(gb + (size_t)t * 1024);
            bf16x8 h1 = *reinterpret_cast<const bf16x8*>(gb + (size_t)t * 1024 + 512);
            const float* wd = wb + t * 64;
            float4 wa = *reinterpret_cast<const float4*>(wd);
            float4 wc = *reinterpret_cast<const float4*>(wd + 4);
            float4 we = *reinterpret_cast<const float4*>(wd + 32);
            float4 wg = *reinterpret_cast<const float4*>(wd + 36);
            dacc += b2f((unsigned short)h0[0]) * wa.x + b2f((unsigned short)h0[1]) * wa.y +
                    b2f((unsigned short)h0[2]) * wa.z + b2f((unsigned short)h0[3]) * wa.w +
                    b2f((unsigned short)h0[4]) * wc.x + b2f((unsigned short)h0[5]) * wc.y +
                    b2f((unsigned short)h0[6]) * wc.z + b2f((unsigned short)h0[7]) * wc.w +
                    b2f((unsigned short)h1[0]) * we.x + b2f((unsigned short)h1[1]) * we.y +
                    b2f((unsigned short)h1[2]) * we.z + b2f((unsigned short)h1[3]) * we.w +
                    b2f((unsigned short)h1[4]) * wg.x + b2f((unsigned short)h1[5]) * wg.y +
                    b2f((unsigned short)h1[6]) * wg.z + b2f((unsigned short)h1[7]) * wg.w;
        }
        float* red = reinterpret_cast<float*>(&hall[0][0]);
        red[(w * 4 + quad) * 16 + l15] = dacc;
        __syncthreads();
        if (tid < 16) {
            float sum = bd[0];
#pragma unroll
            for (int j = 0; j < 32; ++j) sum += red[j * 16 + tid];
            out[s * 16 + tid] = sum;
        }
    }
}

extern "C" void kernel_launch(void* const* d_in, const int* in_sizes, int n_in,
                              void* d_out, int out_size, void* d_ws, size_t ws_size,
                              hipStream_t stream) {
    (void)in_sizes; (void)n_in; (void)out_size; (void)ws_size;
    const float* x   = (const float*)d_in[0];
    const float* Wx1 = (const float*)d_in[1];
    const float* Wh1 = (const float*)d_in[2];
    const float* b1  = (const float*)d_in[3];
    const float* Wx2 = (const float*)d_in[4];
    const float* Wh2 = (const float*)d_in[5];
    const float* b2  = (const float*)d_in[6];
    const float* Wx3 = (const float*)d_in[7];
    const float* Wh3 = (const float*)d_in[8];
    const float* b3  = (const float*)d_in[9];
    const float* Wx4 = (const float*)d_in[10];
    const float* Wh4 = (const float*)d_in[11];
    const float* b4  = (const float*)d_in[12];
    const float* Wd  = (const float*)d_in[13];
    const float* bd  = (const float*)d_in[14];
    float* out = (float*)d_out;

    char* ws = (char*)d_ws;
    unsigned short* xbT = (unsigned short*)(ws);             // 16.8M
    unsigned short* H4  = (unsigned short*)(ws + 16777216);  // 16.8M

    cvt_tile4<<<2048, 256, 0, stream>>>(x, xbT);

    rnn4<<<32, 512, 0, stream>>>(xbT, Wx1, Wh1, b1, Wx2, Wh2, b2,
                                 Wx3, Wh3, b3, Wx4, Wh4, b4, H4, Wd, bd, out);
}